// Round 7
// baseline (781.045 us; speedup 1.0000x reference)
//
#include <hip/hip_runtime.h>
#include <hip/hip_bf16.h>
#include <stdint.h>

#define Bsz 4
#define Nn 4096
#define Dd 512
#define THETA 0.08f
#define CAND_CAP 384

typedef unsigned short u16;
typedef __attribute__((ext_vector_type(8))) short bf16x8;
typedef __attribute__((ext_vector_type(4))) float f32x4;
typedef __attribute__((address_space(3))) uint32_t lds_as;
typedef __attribute__((address_space(1))) const uint32_t gbl_as;

__device__ __forceinline__ u16 bf16_of(float v) {
  __hip_bfloat16 h = __float2bfloat16(v);
  return __builtin_bit_cast(u16, h);
}
__device__ __forceinline__ float f_of_bf16(u16 u) {
  return __uint_as_float(((uint32_t)u) << 16);
}

// ---------------- K1: normalize + split bf16 hi/lo + zero per-row counters ----------------
__global__ __launch_bounds__(128) void prep_kernel(const float* __restrict__ x,
                                                   float* __restrict__ rinv,
                                                   u16* __restrict__ xh,
                                                   u16* __restrict__ xl,
                                                   uint32_t* __restrict__ cnt) {
  int row = blockIdx.x;   // B*N rows
  int t = threadIdx.x;    // 128 threads, one float4 each
  const float4* xr = (const float4*)(x + (size_t)row * Dd);
  float4 v = xr[t];
  float s = v.x * v.x + v.y * v.y + v.z * v.z + v.w * v.w;
  for (int o = 32; o > 0; o >>= 1) s += __shfl_down(s, o, 64);
  __shared__ float ls[2];
  if ((t & 63) == 0) ls[t >> 6] = s;
  __syncthreads();
  float ri = 1.0f / fmaxf(sqrtf(ls[0] + ls[1]), 1e-12f);
  if (t == 0) { rinv[row] = ri; cnt[row] = 0u; }
  float n0 = v.x * ri, n1 = v.y * ri, n2 = v.z * ri, n3 = v.w * ri;
  u16 h0 = bf16_of(n0), h1 = bf16_of(n1), h2 = bf16_of(n2), h3 = bf16_of(n3);
  u16 l0 = bf16_of(n0 - f_of_bf16(h0));
  u16 l1 = bf16_of(n1 - f_of_bf16(h1));
  u16 l2 = bf16_of(n2 - f_of_bf16(h2));
  u16 l3 = bf16_of(n3 - f_of_bf16(h3));
  uint2 hp, lp;
  hp.x = (uint32_t)h0 | ((uint32_t)h1 << 16);
  hp.y = (uint32_t)h2 | ((uint32_t)h3 << 16);
  lp.x = (uint32_t)l0 | ((uint32_t)l1 << 16);
  lp.y = (uint32_t)l2 | ((uint32_t)l3 << 16);
  *(uint2*)(xh + (size_t)row * Dd + t * 4) = hp;
  *(uint2*)(xl + (size_t)row * Dd + t * 4) = lp;
}

// ---------------- K2: symmetric split-bf16 MFMA GEMM -> candidate lists ----------------
// K-loop identical to round 6 (verified). Epilogue filters sims > THETA into
// per-row (value,idx) candidate lists via global atomics; no sim matrix stored.
__global__ __launch_bounds__(256) void gemm_sym(const u16* __restrict__ xh,
                                                const u16* __restrict__ xl,
                                                uint32_t* __restrict__ cnt,
                                                uint2* __restrict__ cand) {
  __shared__ __align__(16) u16 lds[4 * 128 * 32];   // 32 KB
  int b = blockIdx.y;
  int p = blockIdx.x;             // 0..527 upper-triangle tile pairs (T=32)
  const int T = Nn / 128;
  int ti = 0;
  while (p >= T - ti) { p -= T - ti; ti++; }
  int tj = ti + p;
  int ri0 = ti * 128, rj0 = tj * 128;
  int tid = threadIdx.x, wid = tid >> 6, lane = tid & 63;
  int wr = (wid >> 1) * 64, wc = (wid & 1) * 64;   // wave's 64x64 quadrant
  int frow = lane & 15, kg = lane >> 4;

  // staging role: wave wid stages tile wid (0=Ah,1=Al,2=Bh,3=Bl)
  const u16* src = (wid & 1) ? xl : xh;
  int rbase = (wid >> 1) ? rj0 : ri0;
  const u16* sb = src + ((size_t)b * Nn + rbase) * Dd;
  u16* tb = &lds[wid * 4096];
  int lrow = lane >> 2;
  int g = lane & 3;

  f32x4 acc[4][4];
#pragma unroll
  for (int mt = 0; mt < 4; mt++)
#pragma unroll
    for (int nt = 0; nt < 4; nt++) acc[mt][nt] = (f32x4){0.f, 0.f, 0.f, 0.f};

  for (int k0 = 0; k0 < Dd; k0 += 32) {
    __syncthreads();
#pragma unroll
    for (int i = 0; i < 8; i++) {
      int r = i * 16 + lrow;
      int gs = g ^ ((r >> 1) & 3);
      const u16* gp = sb + (size_t)r * Dd + k0 + gs * 8;
      __builtin_amdgcn_global_load_lds((gbl_as*)gp, (lds_as*)(tb + i * 512), 16, 0, 0);
    }
    __syncthreads();

    bf16x8 bhf[4], blf[4];
#pragma unroll
    for (int nt = 0; nt < 4; nt++) {
      int rB = wc + nt * 16 + frow;
      int offB = rB * 32 + ((kg ^ ((rB >> 1) & 3)) * 8);
      bhf[nt] = *(const bf16x8*)&lds[8192 + offB];
      blf[nt] = *(const bf16x8*)&lds[12288 + offB];
    }
#pragma unroll
    for (int mt = 0; mt < 4; mt++) {
      int rA = wr + mt * 16 + frow;
      int offA = rA * 32 + ((kg ^ ((rA >> 1) & 3)) * 8);
      bf16x8 ah = *(const bf16x8*)&lds[offA];
      bf16x8 al = *(const bf16x8*)&lds[4096 + offA];
#pragma unroll
      for (int nt = 0; nt < 4; nt++) {
        acc[mt][nt] = __builtin_amdgcn_mfma_f32_16x16x32_bf16(ah, bhf[nt], acc[mt][nt], 0, 0, 0);
        acc[mt][nt] = __builtin_amdgcn_mfma_f32_16x16x32_bf16(ah, blf[nt], acc[mt][nt], 0, 0, 0);
        acc[mt][nt] = __builtin_amdgcn_mfma_f32_16x16x32_bf16(al, bhf[nt], acc[mt][nt], 0, 0, 0);
      }
    }
  }

  // epilogue: C/D layout col=lane&15, row=(lane>>4)*4+reg; filter > THETA
#pragma unroll
  for (int mt = 0; mt < 4; mt++) {
    int rowg0 = ri0 + wr + mt * 16 + (lane >> 4) * 4;
#pragma unroll
    for (int nt = 0; nt < 4; nt++) {
      int colg = rj0 + wc + nt * 16 + frow;
      float vv[4] = {acc[mt][nt].x, acc[mt][nt].y, acc[mt][nt].z, acc[mt][nt].w};
#pragma unroll
      for (int c = 0; c < 4; c++) {
        float vb = f_of_bf16(bf16_of(vv[c]));   // bf16-rounded sim (round-6 semantics)
        if (vb > THETA) {
          int rg = b * Nn + rowg0 + c;
          uint32_t slot = atomicAdd(&cnt[rg], 1u);
          if (slot < CAND_CAP) cand[(size_t)rg * CAND_CAP + slot] = make_uint2(__float_as_uint(vb), (uint32_t)colg);
          if (ti != tj) {
            int cg = b * Nn + colg;
            uint32_t s2 = atomicAdd(&cnt[cg], 1u);
            if (s2 < CAND_CAP) cand[(size_t)cg * CAND_CAP + s2] = make_uint2(__float_as_uint(vb), (uint32_t)(rowg0 + c));
          }
        }
      }
    }
  }
}

// ---------------- K3: zero the output ----------------
__global__ __launch_bounds__(256) void zero_kernel(float4* __restrict__ o) {
  size_t i = (size_t)blockIdx.x * 256 + threadIdx.x;   // 4096 blocks
#pragma unroll
  for (int k = 0; k < 16; k++)
    o[i + (size_t)k * 1048576] = (float4){0.f, 0.f, 0.f, 0.f};
}

// ---------------- K4: rank candidates + band refinement + scatter ----------------
__global__ __launch_bounds__(256) void select_kernel(const uint32_t* __restrict__ cnt,
                                                     const uint2* __restrict__ cand,
                                                     const float* __restrict__ x,
                                                     const float* __restrict__ rinv,
                                                     float* __restrict__ out) {
  int row = blockIdx.x;   // global row in [0, B*N)
  int t = threadIdx.x;    // 256
  __shared__ float lv[CAND_CAP];
  __shared__ int li[CAND_CAP];
  __shared__ float keepVal[40];
  __shared__ int keepIdx[40];
  __shared__ float bandLv[96], bandV[96];
  __shared__ int bandIdx[96];
  __shared__ int keepCnt, bandCnt, listCnt;
  __shared__ float sS;

  int bb = row >> 12;
  int rl = row & (Nn - 1);
  const float* xn = x + (size_t)row * Dd;
  const float* xbb = x + (((size_t)bb) << 12) * Dd;
  const float* rv = rinv + (bb << 12);
  float ra = rinv[row];

  uint32_t Lraw = cnt[row];
  bool fb = (Lraw < 36u) || (Lraw > (uint32_t)CAND_CAP);
  int L = (int)(Lraw > CAND_CAP ? CAND_CAP : Lraw);
  float S = 0.f, eb = 0.f;

  if (!fb) {
    for (int s = t; s < L; s += 256) {
      uint2 u = cand[(size_t)row * CAND_CAP + s];
      lv[s] = __uint_as_float(u.x);
      li[s] = (int)u.y;
    }
    __syncthreads();
    // exact rank-31 (value desc, index asc) = 32nd largest
    for (int e = t; e < L; e += 256) {
      float ve = lv[e]; int ie = li[e];
      int rank = 0;
      for (int q = 0; q < L; q++) {
        float vq = lv[q]; int iq = li[q];
        rank += ((vq > ve) || (vq == ve && iq < ie)) ? 1 : 0;
      }
      if (rank == 31) sS = ve;
    }
    __syncthreads();
    S = sS;
    eb = fmaxf(3e-4f, fabsf(S) * 4e-3f);
    if (S - eb <= THETA) fb = true;   // band would reach below filter: bail out
  }

  if (fb) {
    // never-taken safety path: full-row fp32 recompute (round-1 chain), exact top-32
    if (t == 0) { listCnt = 0; keepCnt = 0; }
    __syncthreads();
    for (int c = t; c < Nn; c += 256) {
      const float* xm = xbb + (size_t)c * Dd;
      float dot = 0.f;
      for (int k = 0; k < Dd; k += 4) {
        float4 a4 = *(const float4*)(xn + k);
        float4 b4 = *(const float4*)(xm + k);
        dot = fmaf(a4.x, b4.x, dot);
        dot = fmaf(a4.y, b4.y, dot);
        dot = fmaf(a4.z, b4.z, dot);
        dot = fmaf(a4.w, b4.w, dot);
      }
      float v = (dot * ra) * rv[c];
      if (v > 0.05f) {
        int slot = atomicAdd(&listCnt, 1);
        if (slot < CAND_CAP) { lv[slot] = v; li[slot] = c; }
      }
    }
    __syncthreads();
    int Lf = listCnt; if (Lf > CAND_CAP) Lf = CAND_CAP;
    for (int e = t; e < Lf; e += 256) {
      float ve = lv[e]; int ie = li[e];
      int rank = 0;
      for (int q = 0; q < Lf; q++) {
        float vq = lv[q]; int iq = li[q];
        rank += ((vq > ve) || (vq == ve && iq < ie)) ? 1 : 0;
      }
      if (rank < 32) {
        int k = atomicAdd(&keepCnt, 1);
        keepIdx[k] = ie; keepVal[k] = ve;
      }
    }
    __syncthreads();
  } else {
    float hiT = S + eb, loT = S - eb;
    if (t == 0) { keepCnt = 0; bandCnt = 0; }
    __syncthreads();
    for (int s = t; s < L; s += 256) {
      float v = lv[s];
      if (v > hiT) {
        int k = atomicAdd(&keepCnt, 1);
        keepIdx[k] = li[s]; keepVal[k] = v;
      } else if (v >= loT) {
        int bs = atomicAdd(&bandCnt, 1);
        if (bs < 96) { bandIdx[bs] = li[s]; bandLv[bs] = v; }
      }
    }
    __syncthreads();
    int A = keepCnt;
    int BC = bandCnt; if (BC > 96) BC = 96;
    int need = 32 - A;
    bool heavy = (BC > need);
    if (heavy) {
      // resolve band order with the bitwise round-1 fp32 chain
      for (int s = t; s < BC; s += 256) {
        int m = bandIdx[s];
        const float* xm = xbb + (size_t)m * Dd;
        float dot = 0.f;
        for (int k = 0; k < Dd; k += 4) {
          float4 a4 = *(const float4*)(xn + k);
          float4 b4 = *(const float4*)(xm + k);
          dot = fmaf(a4.x, b4.x, dot);
          dot = fmaf(a4.y, b4.y, dot);
          dot = fmaf(a4.z, b4.z, dot);
          dot = fmaf(a4.w, b4.w, dot);
        }
        bandV[s] = (dot * ra) * rv[m];
      }
    }
    __syncthreads();
    if (t == 0) {
      if (!heavy) {
        for (int s = 0; s < BC; s++) { keepIdx[A + s] = bandIdx[s]; keepVal[A + s] = bandLv[s]; }
        keepCnt = A + BC;   // == 32 by rank invariant
      } else {
        int app = 0;
        for (int s = 0; s < need; s++) {
          float bv = -1e30f; int bidx = 0x7FFFFFFF, bs = -1;
          for (int q = 0; q < BC; q++) {
            int gi = bandIdx[q];
            if (gi < 0) continue;
            float v = bandV[q];
            if (v > bv || (v == bv && gi < bidx)) { bv = v; bidx = gi; bs = q; }
          }
          if (bs < 0) break;
          keepIdx[A + app] = bandIdx[bs]; keepVal[A + app] = bandLv[bs];
          bandIdx[bs] = -1; app++;
        }
        keepCnt = A + app;
      }
    }
    __syncthreads();
  }

  int KC = keepCnt;
  if (t < KC) {
    int m = keepIdx[t];
    float hv = 0.5f * keepVal[t];
    float* ob = out + (((size_t)bb) << 24);
    atomicAdd(ob + (size_t)rl * Nn + m, hv);
    atomicAdd(ob + (size_t)m * Nn + rl, hv);
  }
}

extern "C" void kernel_launch(void* const* d_in, const int* in_sizes, int n_in,
                              void* d_out, int out_size, void* d_ws, size_t ws_size,
                              hipStream_t stream) {
  const float* x = (const float*)d_in[0];
  float* out = (float*)d_out;
  // ws layout: rinv 64KB | cnt 64KB | xh 16MB | xl 16MB | cand 50.3MB
  float* rinv = (float*)d_ws;
  uint32_t* cnt = (uint32_t*)((char*)d_ws + 65536);
  u16* xh = (u16*)((char*)d_ws + 131072);
  u16* xl = xh + (size_t)Bsz * Nn * Dd;
  uint2* cand = (uint2*)((char*)d_ws + 131072 + 2 * (size_t)Bsz * Nn * Dd * sizeof(u16));

  prep_kernel<<<Bsz * Nn, 128, 0, stream>>>(x, rinv, xh, xl, cnt);
  dim3 g2(528, Bsz);
  gemm_sym<<<g2, 256, 0, stream>>>(xh, xl, cnt, cand);
  zero_kernel<<<4096, 256, 0, stream>>>((float4*)out);
  select_kernel<<<Bsz * Nn, 256, 0, stream>>>(cnt, cand, x, rinv, out);
}